// Round 6
// baseline (182.522 us; speedup 1.0000x reference)
//
#include <hip/hip_runtime.h>

#define K_CODES 1024
#define DIM 256
#define N_TOT 32768

typedef _Float16 f16;
typedef _Float16 f16x8 __attribute__((ext_vector_type(8)));
typedef _Float16 f16x4 __attribute__((ext_vector_type(4)));
typedef float f32x4 __attribute__((ext_vector_type(4)));

// Exact replica of numpy FLOAT_pairwise_sum for 128 contiguous squares (validated r3).
__device__ __forceinline__ float np_pw128_sq(const float* __restrict__ v) {
    float r[8];
    #pragma unroll
    for (int j = 0; j < 8; ++j) r[j] = __fmul_rn(v[j], v[j]);
    #pragma unroll
    for (int i = 1; i < 16; ++i)
        #pragma unroll
        for (int j = 0; j < 8; ++j)
            r[j] = __fadd_rn(r[j], __fmul_rn(v[8*i+j], v[8*i+j]));
    const float t01 = __fadd_rn(r[0], r[1]);
    const float t23 = __fadd_rn(r[2], r[3]);
    const float t45 = __fadd_rn(r[4], r[5]);
    const float t67 = __fadd_rn(r[6], r[7]);
    return __fadd_rn(__fadd_rn(t01, t23), __fadd_rn(t45, t67));
}

__global__ void vq_wnorm_kernel(const float* __restrict__ weight, float* __restrict__ wnorm) {
    int k = blockIdx.x * blockDim.x + threadIdx.x;
    if (k >= K_CODES) return;
    const float* wr = weight + (size_t)k * DIM;
    wnorm[k] = __fadd_rn(np_pw128_sq(wr), np_pw128_sq(wr + 128));
}

// W -> f16, scaled by 1024 (exact pow2) to avoid f16 denormals.
__global__ void vq_convw_kernel(const float* __restrict__ weight, f16* __restrict__ Wh) {
    const int k = blockIdx.x;          // 1024 blocks x 64 threads
    const int t = threadIdx.x;
    const float4 v = *(const float4*)&weight[(size_t)k * DIM + t * 4];
    f16x4 o;
    o[0] = (f16)(v.x * 1024.0f);
    o[1] = (f16)(v.y * 1024.0f);
    o[2] = (f16)(v.z * 1024.0f);
    o[3] = (f16)(v.w * 1024.0f);
    *(f16x4*)&Wh[(size_t)k * DIM + t * 4] = o;
}

template<bool PRE>
__global__ __launch_bounds__(512, 1) void vq_main_kernel(
    const float* __restrict__ x, const float* __restrict__ weight,
    const float* __restrict__ wnorm, const f16* __restrict__ Wh,
    float* __restrict__ enc_out, float* __restrict__ qf_out,
    float* __restrict__ idx_out, float* __restrict__ q_out)
{
    __shared__ __align__(16) f16 Eh[64][264];          // 33792 B, stride 528 B
    __shared__ __align__(16) char WlRaw[64 * 264 * 2]; // 33792 B: f16 Wl[64][264] | float F[32][260]
    __shared__ float wn[K_CODES];                      // 4096 B
    __shared__ float sE[64];
    __shared__ float rAcc[32][16];
    __shared__ unsigned rm[64];
    __shared__ unsigned long long rmEx[64];

    f16 (*Wl)[264] = (f16(*)[264])WlRaw;
    float (*F)[260] = (float(*)[260])WlRaw;

    const int tid = threadIdx.x;
    const int blk = blockIdx.x;        // 512 blocks: b = blk>>4, hp = blk&15
    const int b  = blk >> 4;
    const int hp = blk & 15;
    const long n0 = (long)blk * 64;    // global row base; local row = s*32 + w

    if (tid < 64) { rm[tid] = 0xFFFFFFFFu; rmEx[tid] = 0xFFFFFFFFFFFFFFFFull; }
    for (int i = tid; i < K_CODES; i += 512) wn[i] = wnorm[i];

    // ================= Phase 1: transpose, enc write, sE, f16 convert ==========
    for (int s = 0; s < 2; ++s) {
        const int h = hp * 2 + s;
        __syncthreads();                               // F free
        {
            const int w = tid & 31, c0 = tid >> 5;
            for (int c = c0; c < DIM; c += 16)
                F[w][c] = x[(((long)b * DIM + c) * 32 + h) * 32 + w];
        }
        __syncthreads();
        {   // encoded_flat write (float4 coalesced)
            const int c4 = tid & 63, rg = tid >> 6;
            #pragma unroll
            for (int r0 = 0; r0 < 32; r0 += 8) {
                const int row = r0 + rg;
                *(float4*)&enc_out[(n0 + s * 32 + row) * DIM + c4 * 4] =
                    *(const float4*)&F[row][c4 * 4];
            }
        }
        {   // numpy pairwise partials: 16 accumulators per row (2 blocks x 8)
            const int r = tid >> 4, half = (tid >> 3) & 1, a = tid & 7;
            const int base = half * 128 + a;
            float acc = __fmul_rn(F[r][base], F[r][base]);
            #pragma unroll
            for (int i = 1; i < 16; ++i) {
                const float e = F[r][base + 8 * i];
                acc = __fadd_rn(acc, __fmul_rn(e, e));
            }
            rAcc[r][half * 8 + a] = acc;
        }
        {   // f16 convert
            const int w = tid & 31, c0 = tid >> 5;
            for (int c = c0; c < DIM; c += 16)
                Eh[s * 32 + w][c] = (f16)F[w][c];
        }
        __syncthreads();
        if (tid < 32) {
            const float* r0 = rAcc[tid];
            const float b0 = __fadd_rn(__fadd_rn(__fadd_rn(r0[0], r0[1]), __fadd_rn(r0[2], r0[3])),
                                       __fadd_rn(__fadd_rn(r0[4], r0[5]), __fadd_rn(r0[6], r0[7])));
            const float b1 = __fadd_rn(__fadd_rn(__fadd_rn(r0[8], r0[9]), __fadd_rn(r0[10], r0[11])),
                                       __fadd_rn(__fadd_rn(r0[12], r0[13]), __fadd_rn(r0[14], r0[15])));
            sE[s * 32 + tid] = __fadd_rn(b0, b1);
        }
    }

    // ================= Phase 2: f16 MFMA distance pass =========================
    const int wid = tid >> 6, lane = tid & 63;
    const int mh = wid >> 2, qw = wid & 3;     // M-half (rows mh*32..), code-quarter of chunk
    const int fr = lane & 15, fg = lane >> 4;

    // A-fragments: 2 M-tiles x 8 K-steps, held in regs (64 VGPR)
    f16x8 afr[2][8];
    #pragma unroll
    for (int mt = 0; mt < 2; ++mt)
        #pragma unroll
        for (int kk = 0; kk < 8; ++kk)
            afr[mt][kk] = *(const f16x8*)&Eh[mh * 32 + mt * 16 + fr][kk * 32 + fg * 8];

    unsigned s1[8], s2[8];                     // per-slot top-2 packed (v_q<<10 | k)
    #pragma unroll
    for (int i = 0; i < 8; ++i) { s1[i] = 0xFFFFFFFFu; s2[i] = 0xFFFFFFFFu; }

    for (int ch = 0; ch < 16; ++ch) {          // 16 chunks of 64 codes
        __syncthreads();
        if (PRE) {
            #pragma unroll
            for (int u = 0; u < 4; ++u) {
                const int flat = u * 512 + tid;        // 0..2047 16B-units; 32 units/code row
                const int code = flat >> 5, seg = flat & 31;
                *(f16x8*)&Wl[code][seg * 8] =
                    *(const f16x8*)&Wh[((long)(ch * 64 + code)) * DIM + seg * 8];
            }
        } else {
            #pragma unroll
            for (int u = 0; u < 4; ++u) {
                const int flat = u * 512 + tid;
                const int code = flat >> 5, seg = flat & 31;
                const float4 v0 = *(const float4*)&weight[((long)(ch * 64 + code)) * DIM + seg * 8];
                const float4 v1 = *(const float4*)&weight[((long)(ch * 64 + code)) * DIM + seg * 8 + 4];
                f16x8 t;
                t[0] = (f16)(v0.x * 1024.0f); t[1] = (f16)(v0.y * 1024.0f);
                t[2] = (f16)(v0.z * 1024.0f); t[3] = (f16)(v0.w * 1024.0f);
                t[4] = (f16)(v1.x * 1024.0f); t[5] = (f16)(v1.y * 1024.0f);
                t[6] = (f16)(v1.z * 1024.0f); t[7] = (f16)(v1.w * 1024.0f);
                *(f16x8*)&Wl[code][seg * 8] = t;
            }
        }
        __syncthreads();

        f32x4 acc0 = {0.f, 0.f, 0.f, 0.f}, acc1 = {0.f, 0.f, 0.f, 0.f};
        #pragma unroll
        for (int kk = 0; kk < 8; ++kk) {
            const f16x8 bfr = *(const f16x8*)&Wl[qw * 16 + fr][kk * 32 + fg * 8];
            acc0 = __builtin_amdgcn_mfma_f32_16x16x32_f16(afr[0][kk], bfr, acc0, 0, 0, 0);
            acc1 = __builtin_amdgcn_mfma_f32_16x16x32_f16(afr[1][kk], bfr, acc1, 0, 0, 0);
        }

        const int code = ch * 64 + qw * 16 + fr;
        const float wnk = wn[code];
        #pragma unroll
        for (int q = 0; q < 4; ++q) {
            {   // M-tile 0: slot q
                const float vp = fmaf(acc0[q], -0.001953125f, wnk);   // wn - 2*dot (dot scaled /1024)
                const unsigned uq = (unsigned)fmaf(vp, 1048576.0f, 1048576.0f);
                const unsigned u = uq * 1024u + (unsigned)code;
                s2[q] = min(s2[q], max(s1[q], u));
                s1[q] = min(s1[q], u);
            }
            {   // M-tile 1: slot 4+q
                const float vp = fmaf(acc1[q], -0.001953125f, wnk);
                const unsigned uq = (unsigned)fmaf(vp, 1048576.0f, 1048576.0f);
                const unsigned u = uq * 1024u + (unsigned)code;
                s2[4 + q] = min(s2[4 + q], max(s1[4 + q], u));
                s1[4 + q] = min(s1[4 + q], u);
            }
        }
    }

    // approximate global min per row
    #pragma unroll
    for (int sl = 0; sl < 8; ++sl) {
        unsigned bmin = s1[sl];
        bmin = min(bmin, (unsigned)__shfl_xor((int)bmin, 1));
        bmin = min(bmin, (unsigned)__shfl_xor((int)bmin, 2));
        bmin = min(bmin, (unsigned)__shfl_xor((int)bmin, 4));
        bmin = min(bmin, (unsigned)__shfl_xor((int)bmin, 8));
        if (fr == 0) {
            const int row = mh * 32 + (sl >> 2) * 16 + fg * 4 + (sl & 3);
            atomicMin(&rm[row], bmin);
        }
    }
    __syncthreads();

    // ================= Phase 3: exact fp32 re-check (numpy-bit-exact, r3 recipe) ==
    #pragma unroll
    for (int sl = 0; sl < 8; ++sl) {
        const int row = mh * 32 + (sl >> 2) * 16 + fg * 4 + (sl & 3);
        const unsigned thr = (rm[row] >> 10) + 1000u;  // margin ~9.5e-4: ~60x f16-pass max error
        #pragma unroll
        for (int c = 0; c < 2; ++c) {
            const unsigned u = c ? s2[sl] : s1[sl];
            if ((u >> 10) <= thr) {
                const int k = (int)(u & 1023u);
                const float* ep = enc_out + (n0 + row) * DIM;
                const float* wp = weight + (long)k * DIM;
                float dot = 0.0f;
                for (int d4 = 0; d4 < 64; ++d4) {      // d strictly ascending
                    const float4 ev = *(const float4*)&ep[d4 * 4];
                    const float4 wv = *(const float4*)&wp[d4 * 4];
                    dot = __fmaf_rn(ev.x, wv.x, dot);
                    dot = __fmaf_rn(ev.y, wv.y, dot);
                    dot = __fmaf_rn(ev.z, wv.z, dot);
                    dot = __fmaf_rn(ev.w, wv.w, dot);
                }
                const float vex = __fadd_rn(__fadd_rn(sE[row], -__fmul_rn(2.0f, dot)), wn[k]);
                const unsigned long long pk =
                    (((unsigned long long)__float_as_uint(vex)) << 10) | (unsigned long long)k;
                atomicMin(&rmEx[row], pk);
            }
        }
    }
    __syncthreads();

    if (tid < 64) idx_out[n0 + tid] = (float)(unsigned)(rmEx[tid] & 1023ull);

    // ================= Phase 4/5: gather codes -> qf + NCHW scatter ============
    for (int s = 0; s < 2; ++s) {
        __syncthreads();                               // F (=Wl) free
        {
            const int c4 = tid & 63, rg = tid >> 6;
            #pragma unroll
            for (int r0 = 0; r0 < 32; r0 += 8) {
                const int row = r0 + rg;
                const int k = (int)(unsigned)(rmEx[s * 32 + row] & 1023ull);
                const float4 v = *(const float4*)&weight[(long)k * DIM + c4 * 4];
                *(float4*)&qf_out[(n0 + s * 32 + row) * DIM + c4 * 4] = v;
                *(float4*)&F[row][c4 * 4] = v;
            }
        }
        __syncthreads();
        {
            const int w = tid & 31, c0 = tid >> 5;
            const int h = hp * 2 + s;
            for (int c = c0; c < DIM; c += 16)
                q_out[(((long)b * DIM + c) * 32 + h) * 32 + w] = F[w][c];
        }
    }
}

extern "C" void kernel_launch(void* const* d_in, const int* in_sizes, int n_in,
                              void* d_out, int out_size, void* d_ws, size_t ws_size,
                              hipStream_t stream)
{
    const float* x      = (const float*)d_in[0];   // [32,256,32,32]
    const float* weight = (const float*)d_in[1];   // [1024,256]

    float* out = (float*)d_out;
    float* enc = out;                                   // [32768,256]
    float* qf  = enc + (size_t)N_TOT * DIM;             // [32768,256]
    float* idx = qf  + (size_t)N_TOT * DIM;             // [32768] as float
    float* qo  = idx + N_TOT;                           // [32,256,32,32]

    float* wnorm = (float*)d_ws;                        // 4 KB
    f16*   Wh    = (f16*)((char*)d_ws + 4096);          // 512 KB (if it fits)

    const bool pre = ws_size >= (size_t)(4096 + K_CODES * DIM * 2 + 64);

    vq_wnorm_kernel<<<K_CODES / 256, 256, 0, stream>>>(weight, wnorm);
    if (pre) {
        vq_convw_kernel<<<K_CODES, 64, 0, stream>>>(weight, Wh);
        vq_main_kernel<true><<<512, 512, 0, stream>>>(x, weight, wnorm, Wh, enc, qf, idx, qo);
    } else {
        vq_main_kernel<false><<<512, 512, 0, stream>>>(x, weight, wnorm, Wh, enc, qf, idx, qo);
    }
}

// Round 7
// 144.321 us; speedup vs baseline: 1.2647x; 1.2647x over previous
//
#include <hip/hip_runtime.h>

#define K_CODES 1024
#define DIM 256
#define N_TOT 32768
#define LCAP 768

typedef _Float16 f16;
typedef _Float16 f16x8 __attribute__((ext_vector_type(8)));
typedef _Float16 f16x4 __attribute__((ext_vector_type(4)));
typedef float f32x4 __attribute__((ext_vector_type(4)));

// Exact replica of numpy FLOAT_pairwise_sum for 128 contiguous squares (validated r3).
__device__ __forceinline__ float np_pw128_sq(const float* __restrict__ v) {
    float r[8];
    #pragma unroll
    for (int j = 0; j < 8; ++j) r[j] = __fmul_rn(v[j], v[j]);
    #pragma unroll
    for (int i = 1; i < 16; ++i)
        #pragma unroll
        for (int j = 0; j < 8; ++j)
            r[j] = __fadd_rn(r[j], __fmul_rn(v[8*i+j], v[8*i+j]));
    const float t01 = __fadd_rn(r[0], r[1]);
    const float t23 = __fadd_rn(r[2], r[3]);
    const float t45 = __fadd_rn(r[4], r[5]);
    const float t67 = __fadd_rn(r[6], r[7]);
    return __fadd_rn(__fadd_rn(t01, t23), __fadd_rn(t45, t67));
}

__global__ void vq_wnorm_kernel(const float* __restrict__ weight, float* __restrict__ wnorm) {
    int k = blockIdx.x * blockDim.x + threadIdx.x;
    if (k >= K_CODES) return;
    const float* wr = weight + (size_t)k * DIM;
    wnorm[k] = __fadd_rn(np_pw128_sq(wr), np_pw128_sq(wr + 128));
}

// W -> f16, scaled by 1024 (exact pow2) to avoid f16 denormals.
__global__ void vq_convw_kernel(const float* __restrict__ weight, f16* __restrict__ Wh) {
    const int k = blockIdx.x;          // 1024 blocks x 64 threads
    const int t = threadIdx.x;
    const float4 v = *(const float4*)&weight[(size_t)k * DIM + t * 4];
    f16x4 o;
    o[0] = (f16)(v.x * 1024.0f);
    o[1] = (f16)(v.y * 1024.0f);
    o[2] = (f16)(v.z * 1024.0f);
    o[3] = (f16)(v.w * 1024.0f);
    *(f16x4*)&Wh[(size_t)k * DIM + t * 4] = o;
}

template<bool PRE>
__global__ __launch_bounds__(512, 2) void vq_main_kernel(
    const float* __restrict__ x, const float* __restrict__ weight,
    const float* __restrict__ wnorm, const f16* __restrict__ Wh,
    float* __restrict__ enc_out, float* __restrict__ qf_out,
    float* __restrict__ idx_out, float* __restrict__ q_out)
{
    // Wl[2][64][260] f16 double-buffer (66560 B); F (fp32 [32][260], 33280 B) overlays Wl[0].
    __shared__ __align__(16) char WlRaw[2 * 64 * 260 * 2];
    __shared__ float wn[K_CODES];                      // 4096 B
    __shared__ float sE[64];
    __shared__ float rAcc[32][16];
    __shared__ unsigned rm[64];
    __shared__ unsigned long long rmEx[64];
    __shared__ unsigned list[LCAP];
    __shared__ unsigned lcount;

    f16 (*Wl)[64][260] = (f16(*)[64][260])WlRaw;
    float (*F)[260] = (float(*)[260])WlRaw;

    const int tid = threadIdx.x;
    const int blk = blockIdx.x;        // 512 blocks: b = blk>>4, hp = blk&15
    const int b  = blk >> 4;
    const int hp = blk & 15;
    const long n0 = (long)blk * 64;    // global row base; local row = s*32 + w

    const int wid = tid >> 6, lane = tid & 63;
    const int mh = wid >> 2, qw = wid & 3;     // rows-half, code-quarter of chunk
    const int fr = lane & 15, fg = lane >> 4;

    if (tid < 64) { rm[tid] = 0xFFFFFFFFu; rmEx[tid] = 0xFFFFFFFFFFFFFFFFull; }
    if (tid == 0) lcount = 0;
    for (int i = tid; i < K_CODES; i += 512) wn[i] = wnorm[i];

    f16x8 afr[2][8];   // A fragments: 2 M-tiles x 8 K-steps, register-resident (64 VGPR)

    // ================= Phase 1: transpose, enc write, sE, afr extract ==========
    for (int s = 0; s < 2; ++s) {
        const int h = hp * 2 + s;
        __syncthreads();                               // F free
        {
            const int w = tid & 31, c0 = tid >> 5;
            for (int c = c0; c < DIM; c += 16)
                F[w][c] = x[(((long)b * DIM + c) * 32 + h) * 32 + w];
        }
        __syncthreads();
        {   // encoded_flat write (float4 coalesced)
            const int c4 = tid & 63, rg = tid >> 6;
            #pragma unroll
            for (int r0 = 0; r0 < 32; r0 += 8) {
                const int row = r0 + rg;
                *(float4*)&enc_out[(n0 + s * 32 + row) * DIM + c4 * 4] =
                    *(const float4*)&F[row][c4 * 4];
            }
        }
        {   // numpy pairwise partials: 16 accumulators per row (2 blocks x 8)
            const int r = tid >> 4, half = (tid >> 3) & 1, a = tid & 7;
            const int base = half * 128 + a;
            float acc = __fmul_rn(F[r][base], F[r][base]);
            #pragma unroll
            for (int i = 1; i < 16; ++i) {
                const float e = F[r][base + 8 * i];
                acc = __fadd_rn(acc, __fmul_rn(e, e));
            }
            rAcc[r][half * 8 + a] = acc;
        }
        if (mh == s) {   // extract this wave's A-fragments (f32 -> f16 in regs)
            #pragma unroll
            for (int mt = 0; mt < 2; ++mt)
                #pragma unroll
                for (int kk = 0; kk < 8; ++kk) {
                    f16x8 a;
                    #pragma unroll
                    for (int hh = 0; hh < 2; ++hh) {
                        const float4 v = *(const float4*)&F[mt * 16 + fr][kk * 32 + fg * 8 + hh * 4];
                        a[hh * 4 + 0] = (f16)v.x; a[hh * 4 + 1] = (f16)v.y;
                        a[hh * 4 + 2] = (f16)v.z; a[hh * 4 + 3] = (f16)v.w;
                    }
                    afr[mt][kk] = a;
                }
        }
        __syncthreads();
        if (tid < 32) {
            const float* r0 = rAcc[tid];
            const float b0 = __fadd_rn(__fadd_rn(__fadd_rn(r0[0], r0[1]), __fadd_rn(r0[2], r0[3])),
                                       __fadd_rn(__fadd_rn(r0[4], r0[5]), __fadd_rn(r0[6], r0[7])));
            const float b1 = __fadd_rn(__fadd_rn(__fadd_rn(r0[8], r0[9]), __fadd_rn(r0[10], r0[11])),
                                       __fadd_rn(__fadd_rn(r0[12], r0[13]), __fadd_rn(r0[14], r0[15])));
            sE[s * 32 + tid] = __fadd_rn(b0, b1);
        }
    }

    // ================= Phase 2: f16 MFMA pass, double-buffered staging =========
    unsigned s1[8], s2[8];                     // per-slot top-2 packed (v_q<<10 | k)
    #pragma unroll
    for (int i = 0; i < 8; ++i) { s1[i] = 0xFFFFFFFFu; s2[i] = 0xFFFFFFFFu; }

    f16x8 streg[4];                            // staging regs: 64 B/thread
    #pragma unroll
    for (int u = 0; u < 4; ++u) {              // issue chunk 0 loads
        const int flat = u * 512 + tid;
        const int code = flat >> 5, seg = flat & 31;
        if (PRE) {
            streg[u] = *(const f16x8*)&Wh[((long)code) * DIM + seg * 8];
        } else {
            const float4 v0 = *(const float4*)&weight[((long)code) * DIM + seg * 8];
            const float4 v1 = *(const float4*)&weight[((long)code) * DIM + seg * 8 + 4];
            f16x8 t;
            t[0]=(f16)(v0.x*1024.f); t[1]=(f16)(v0.y*1024.f); t[2]=(f16)(v0.z*1024.f); t[3]=(f16)(v0.w*1024.f);
            t[4]=(f16)(v1.x*1024.f); t[5]=(f16)(v1.y*1024.f); t[6]=(f16)(v1.z*1024.f); t[7]=(f16)(v1.w*1024.f);
            streg[u] = t;
        }
    }

    #pragma unroll 2
    for (int ch = 0; ch < 16; ++ch) {
        const int buf = ch & 1;
        __syncthreads();                       // prior readers of Wl[buf] done
        #pragma unroll
        for (int u = 0; u < 4; ++u) {          // write staged regs -> LDS
            const int flat = u * 512 + tid;
            const int code = flat >> 5, seg = flat & 31;
            *(f16x8*)&Wl[buf][code][seg * 8] = streg[u];
        }
        if (ch < 15) {                         // issue next chunk's loads (fly during compute)
            #pragma unroll
            for (int u = 0; u < 4; ++u) {
                const int flat = u * 512 + tid;
                const int code = flat >> 5, seg = flat & 31;
                if (PRE) {
                    streg[u] = *(const f16x8*)&Wh[((long)((ch + 1) * 64 + code)) * DIM + seg * 8];
                } else {
                    const float4 v0 = *(const float4*)&weight[((long)((ch + 1) * 64 + code)) * DIM + seg * 8];
                    const float4 v1 = *(const float4*)&weight[((long)((ch + 1) * 64 + code)) * DIM + seg * 8 + 4];
                    f16x8 t;
                    t[0]=(f16)(v0.x*1024.f); t[1]=(f16)(v0.y*1024.f); t[2]=(f16)(v0.z*1024.f); t[3]=(f16)(v0.w*1024.f);
                    t[4]=(f16)(v1.x*1024.f); t[5]=(f16)(v1.y*1024.f); t[6]=(f16)(v1.z*1024.f); t[7]=(f16)(v1.w*1024.f);
                    streg[u] = t;
                }
            }
        }
        __syncthreads();                       // Wl[buf] ready

        f32x4 acc0 = {0.f, 0.f, 0.f, 0.f}, acc1 = {0.f, 0.f, 0.f, 0.f};
        #pragma unroll
        for (int kk = 0; kk < 8; ++kk) {
            const f16x8 bfr = *(const f16x8*)&Wl[buf][qw * 16 + fr][kk * 32 + fg * 8];
            acc0 = __builtin_amdgcn_mfma_f32_16x16x32_f16(afr[0][kk], bfr, acc0, 0, 0, 0);
            acc1 = __builtin_amdgcn_mfma_f32_16x16x32_f16(afr[1][kk], bfr, acc1, 0, 0, 0);
        }

        const int code = ch * 64 + qw * 16 + fr;
        const float wnk = wn[code];
        #pragma unroll
        for (int q = 0; q < 4; ++q) {
            {   // M-tile 0: slot q   (vp = wn - 2*dot; sE is row-constant, argmin-neutral)
                const float vp = fmaf(acc0[q], -0.001953125f, wnk);
                const unsigned uq = (unsigned)fmaf(vp, 1048576.0f, 1048576.0f);
                const unsigned u = uq * 1024u + (unsigned)code;
                s2[q] = min(s2[q], max(s1[q], u));
                s1[q] = min(s1[q], u);
            }
            {   // M-tile 1: slot 4+q
                const float vp = fmaf(acc1[q], -0.001953125f, wnk);
                const unsigned uq = (unsigned)fmaf(vp, 1048576.0f, 1048576.0f);
                const unsigned u = uq * 1024u + (unsigned)code;
                s2[4 + q] = min(s2[4 + q], max(s1[4 + q], u));
                s1[4 + q] = min(s1[4 + q], u);
            }
        }
    }

    // approximate global min per row
    #pragma unroll
    for (int sl = 0; sl < 8; ++sl) {
        unsigned bmin = s1[sl];
        bmin = min(bmin, (unsigned)__shfl_xor((int)bmin, 1));
        bmin = min(bmin, (unsigned)__shfl_xor((int)bmin, 2));
        bmin = min(bmin, (unsigned)__shfl_xor((int)bmin, 4));
        bmin = min(bmin, (unsigned)__shfl_xor((int)bmin, 8));
        if (fr == 0) {
            const int row = mh * 32 + (sl >> 2) * 16 + fg * 4 + (sl & 3);
            atomicMin(&rm[row], bmin);
        }
    }
    __syncthreads();

    // ========== Phase 3: candidate compaction + parallel exact fp32 re-check ====
    auto exact_check = [&](int row, int k) {
        const float* ep = enc_out + (n0 + row) * DIM;
        const float* wp = weight + (long)k * DIM;
        float dot = 0.0f;
        for (int d4 = 0; d4 < 64; ++d4) {      // d strictly ascending, single FMA chain
            const float4 ev = *(const float4*)&ep[d4 * 4];
            const float4 wv = *(const float4*)&wp[d4 * 4];
            dot = __fmaf_rn(ev.x, wv.x, dot);
            dot = __fmaf_rn(ev.y, wv.y, dot);
            dot = __fmaf_rn(ev.z, wv.z, dot);
            dot = __fmaf_rn(ev.w, wv.w, dot);
        }
        const float vex = __fadd_rn(__fadd_rn(sE[row], -__fmul_rn(2.0f, dot)), wn[k]);
        const unsigned long long pk =
            (((unsigned long long)__float_as_uint(vex)) << 10) | (unsigned long long)k;
        atomicMin(&rmEx[row], pk);
    };

    #pragma unroll
    for (int sl = 0; sl < 8; ++sl) {           // 3a: build candidate list
        const int row = mh * 32 + (sl >> 2) * 16 + fg * 4 + (sl & 3);
        const unsigned thr = (rm[row] >> 10) + 1000u;  // ~9.5e-4 window, ~60x f16 max error
        #pragma unroll
        for (int c = 0; c < 2; ++c) {
            const unsigned u = c ? s2[sl] : s1[sl];
            if ((u >> 10) <= thr) {
                const unsigned pos = atomicAdd(&lcount, 1u);
                if (pos < LCAP) list[pos] = ((unsigned)row << 10) | (u & 1023u);
                else exact_check(row, (int)(u & 1023u));   // overflow fallback (never in practice)
            }
        }
    }
    __syncthreads();
    {                                           // 3b: one parallel exact pass
        const unsigned cnt = min(lcount, (unsigned)LCAP);
        for (unsigned t = tid; t < cnt; t += 512) {
            const unsigned ent = list[t];
            exact_check((int)(ent >> 10), (int)(ent & 1023u));
        }
    }
    __syncthreads();

    if (tid < 64) idx_out[n0 + tid] = (float)(unsigned)(rmEx[tid] & 1023ull);

    // ================= Phase 4/5: gather codes -> qf + NCHW scatter ============
    for (int s = 0; s < 2; ++s) {
        __syncthreads();                               // F (=Wl[0]) free
        {
            const int c4 = tid & 63, rg = tid >> 6;
            #pragma unroll
            for (int r0 = 0; r0 < 32; r0 += 8) {
                const int row = r0 + rg;
                const int k = (int)(unsigned)(rmEx[s * 32 + row] & 1023ull);
                const float4 v = *(const float4*)&weight[(long)k * DIM + c4 * 4];
                *(float4*)&qf_out[(n0 + s * 32 + row) * DIM + c4 * 4] = v;
                *(float4*)&F[row][c4 * 4] = v;
            }
        }
        __syncthreads();
        {
            const int w = tid & 31, c0 = tid >> 5;
            const int h = hp * 2 + s;
            for (int c = c0; c < DIM; c += 16)
                q_out[(((long)b * DIM + c) * 32 + h) * 32 + w] = F[w][c];
        }
    }
}

extern "C" void kernel_launch(void* const* d_in, const int* in_sizes, int n_in,
                              void* d_out, int out_size, void* d_ws, size_t ws_size,
                              hipStream_t stream)
{
    const float* x      = (const float*)d_in[0];   // [32,256,32,32]
    const float* weight = (const float*)d_in[1];   // [1024,256]

    float* out = (float*)d_out;
    float* enc = out;                                   // [32768,256]
    float* qf  = enc + (size_t)N_TOT * DIM;             // [32768,256]
    float* idx = qf  + (size_t)N_TOT * DIM;             // [32768] as float
    float* qo  = idx + N_TOT;                           // [32,256,32,32]

    float* wnorm = (float*)d_ws;                        // 4 KB
    f16*   Wh    = (f16*)((char*)d_ws + 4096);          // 512 KB (if it fits)

    const bool pre = ws_size >= (size_t)(4096 + K_CODES * DIM * 2 + 64);

    vq_wnorm_kernel<<<K_CODES / 256, 256, 0, stream>>>(weight, wnorm);
    if (pre) {
        vq_convw_kernel<<<K_CODES, 64, 0, stream>>>(weight, Wh);
        vq_main_kernel<true><<<512, 512, 0, stream>>>(x, weight, wnorm, Wh, enc, qf, idx, qo);
    } else {
        vq_main_kernel<false><<<512, 512, 0, stream>>>(x, weight, wnorm, Wh, enc, qf, idx, qo);
    }
}

// Round 8
// 136.973 us; speedup vs baseline: 1.3325x; 1.0536x over previous
//
#include <hip/hip_runtime.h>

#define K_CODES 1024
#define DIM 256
#define N_TOT 32768
#define LCAP 512

typedef _Float16 f16;
typedef _Float16 f16x8 __attribute__((ext_vector_type(8)));
typedef _Float16 f16x4 __attribute__((ext_vector_type(4)));
typedef float f32x4 __attribute__((ext_vector_type(4)));

// Exact replica of numpy FLOAT_pairwise_sum for 128 contiguous squares (validated r3).
__device__ __forceinline__ float np_pw128_sq(const float* __restrict__ v) {
    float r[8];
    #pragma unroll
    for (int j = 0; j < 8; ++j) r[j] = __fmul_rn(v[j], v[j]);
    #pragma unroll
    for (int i = 1; i < 16; ++i)
        #pragma unroll
        for (int j = 0; j < 8; ++j)
            r[j] = __fadd_rn(r[j], __fmul_rn(v[8*i+j], v[8*i+j]));
    const float t01 = __fadd_rn(r[0], r[1]);
    const float t23 = __fadd_rn(r[2], r[3]);
    const float t45 = __fadd_rn(r[4], r[5]);
    const float t67 = __fadd_rn(r[6], r[7]);
    return __fadd_rn(__fadd_rn(t01, t23), __fadd_rn(t45, t67));
}

__global__ void vq_wnorm_kernel(const float* __restrict__ weight, float* __restrict__ wnorm) {
    int k = blockIdx.x * blockDim.x + threadIdx.x;
    if (k >= K_CODES) return;
    const float* wr = weight + (size_t)k * DIM;
    wnorm[k] = __fadd_rn(np_pw128_sq(wr), np_pw128_sq(wr + 128));
}

// W -> f16, scaled by 1024 (exact pow2) to avoid f16 denormals.
__global__ void vq_convw_kernel(const float* __restrict__ weight, f16* __restrict__ Wh) {
    const int k = blockIdx.x;          // 1024 blocks x 64 threads
    const int t = threadIdx.x;
    const float4 v = *(const float4*)&weight[(size_t)k * DIM + t * 4];
    f16x4 o;
    o[0] = (f16)(v.x * 1024.0f);
    o[1] = (f16)(v.y * 1024.0f);
    o[2] = (f16)(v.z * 1024.0f);
    o[3] = (f16)(v.w * 1024.0f);
    *(f16x4*)&Wh[(size_t)k * DIM + t * 4] = o;
}

// ================= K1: transpose x -> encoded_flat ==========================
__global__ __launch_bounds__(256) void vq_prep_kernel(
    const float* __restrict__ x, float* __restrict__ enc_out)
{
    __shared__ __align__(16) float F[32][260];   // 33280 B
    const int tid = threadIdx.x;
    const int blk = blockIdx.x;        // = b*32 + h
    const int b = blk >> 5, h = blk & 31;
    const long n0 = (long)blk * 32;

    {   // coalesced float4 over w
        const int wq = tid & 7, cb = tid >> 3;   // cb 0..31
        for (int c = cb; c < DIM; c += 32) {
            const float4 v = *(const float4*)&x[(((long)b * DIM + c) * 32 + h) * 32 + wq * 4];
            F[wq * 4 + 0][c] = v.x; F[wq * 4 + 1][c] = v.y;
            F[wq * 4 + 2][c] = v.z; F[wq * 4 + 3][c] = v.w;
        }
    }
    __syncthreads();
    {   // contiguous float4 rows out
        const int c4 = tid & 63, rg = tid >> 6;  // rg 0..3
        #pragma unroll
        for (int r0 = 0; r0 < 32; r0 += 4) {
            const int row = r0 + rg;
            *(float4*)&enc_out[(n0 + row) * DIM + c4 * 4] = *(const float4*)&F[row][c4 * 4];
        }
    }
}

// ================= K2: MFMA distance + argmin (barrier-free hot loop) =======
template<bool PRE>
__global__ __launch_bounds__(512, 2) void vq_dist_kernel(
    const float* __restrict__ enc, const float* __restrict__ weight,
    const float* __restrict__ wnorm, const f16* __restrict__ Wh,
    float* __restrict__ idx_out)
{
    __shared__ float wn[K_CODES];                  // 4 KB
    __shared__ unsigned rm[64];
    __shared__ unsigned long long rmEx[64];
    __shared__ unsigned list[LCAP];
    __shared__ unsigned lcount;

    const int tid = threadIdx.x;
    const long n0 = (long)blockIdx.x * 64;         // 512 blocks x 64 rows
    const int wid = tid >> 6, lane = tid & 63;
    const int mh = wid >> 2, qw = wid & 3;         // row-half, 256-code quarter
    const int fr = lane & 15, fg = lane >> 4;

    if (tid < 64) { rm[tid] = 0xFFFFFFFFu; rmEx[tid] = 0xFFFFFFFFFFFFFFFFull; }
    if (tid == 0) lcount = 0;
    for (int i = tid; i < K_CODES; i += 512) wn[i] = wnorm[i];

    // A-fragments from enc (fp32 -> f16 in regs); 64 VGPR
    f16x8 afr[2][8];
    #pragma unroll
    for (int mt = 0; mt < 2; ++mt)
        #pragma unroll
        for (int kk = 0; kk < 8; ++kk) {
            const int row = mh * 32 + mt * 16 + fr;
            const float4 lo = *(const float4*)&enc[(n0 + row) * DIM + kk * 32 + fg * 8];
            const float4 hi = *(const float4*)&enc[(n0 + row) * DIM + kk * 32 + fg * 8 + 4];
            f16x8 a;
            a[0] = (f16)lo.x; a[1] = (f16)lo.y; a[2] = (f16)lo.z; a[3] = (f16)lo.w;
            a[4] = (f16)hi.x; a[5] = (f16)hi.y; a[6] = (f16)hi.z; a[7] = (f16)hi.w;
            afr[mt][kk] = a;
        }
    __syncthreads();                               // init visible before merge phase

    unsigned s1[8], s2[8];                         // per-slot top-2 packed (v_q<<10 | k)
    #pragma unroll
    for (int i = 0; i < 8; ++i) { s1[i] = 0xFFFFFFFFu; s2[i] = 0xFFFFFFFFu; }

    #pragma unroll 2
    for (int ct = 0; ct < 16; ++ct) {              // this wave: codes qw*256 + ct*16 + fr
        const int code = qw * 256 + ct * 16 + fr;
        f32x4 acc0 = {0.f, 0.f, 0.f, 0.f}, acc1 = {0.f, 0.f, 0.f, 0.f};
        #pragma unroll
        for (int kk = 0; kk < 8; ++kk) {
            f16x8 bfr;
            if (PRE) {
                bfr = *(const f16x8*)&Wh[(long)code * DIM + kk * 32 + fg * 8];
            } else {
                const float4 v0 = *(const float4*)&weight[(long)code * DIM + kk * 32 + fg * 8];
                const float4 v1 = *(const float4*)&weight[(long)code * DIM + kk * 32 + fg * 8 + 4];
                f16x8 t;
                t[0]=(f16)(v0.x*1024.f); t[1]=(f16)(v0.y*1024.f); t[2]=(f16)(v0.z*1024.f); t[3]=(f16)(v0.w*1024.f);
                t[4]=(f16)(v1.x*1024.f); t[5]=(f16)(v1.y*1024.f); t[6]=(f16)(v1.z*1024.f); t[7]=(f16)(v1.w*1024.f);
                bfr = t;
            }
            acc0 = __builtin_amdgcn_mfma_f32_16x16x32_f16(afr[0][kk], bfr, acc0, 0, 0, 0);
            acc1 = __builtin_amdgcn_mfma_f32_16x16x32_f16(afr[1][kk], bfr, acc1, 0, 0, 0);
        }
        const float wnk = wn[code];
        #pragma unroll
        for (int q = 0; q < 4; ++q) {
            {   // M-tile 0 (slot q): vp = wn - 2*dot (dot scaled /1024)
                const float vp = fmaf(acc0[q], -0.001953125f, wnk);
                const unsigned uq = (unsigned)fmaf(vp, 1048576.0f, 1048576.0f);
                const unsigned u = uq * 1024u + (unsigned)code;
                s2[q] = min(s2[q], max(s1[q], u));
                s1[q] = min(s1[q], u);
            }
            {   // M-tile 1 (slot 4+q)
                const float vp = fmaf(acc1[q], -0.001953125f, wnk);
                const unsigned uq = (unsigned)fmaf(vp, 1048576.0f, 1048576.0f);
                const unsigned u = uq * 1024u + (unsigned)code;
                s2[4 + q] = min(s2[4 + q], max(s1[4 + q], u));
                s1[4 + q] = min(s1[4 + q], u);
            }
        }
    }

    // wave-local min over fr lanes, then merge 4 qw-waves via LDS atomicMin
    #pragma unroll
    for (int sl = 0; sl < 8; ++sl) {
        unsigned bmin = s1[sl];
        bmin = min(bmin, (unsigned)__shfl_xor((int)bmin, 1));
        bmin = min(bmin, (unsigned)__shfl_xor((int)bmin, 2));
        bmin = min(bmin, (unsigned)__shfl_xor((int)bmin, 4));
        bmin = min(bmin, (unsigned)__shfl_xor((int)bmin, 8));
        if (fr == 0) {
            const int row = mh * 32 + (sl >> 2) * 16 + fg * 4 + (sl & 3);
            atomicMin(&rm[row], bmin);
        }
    }
    __syncthreads();

    // exact fp32 re-check (numpy-bit-exact r3 recipe; sE computed inline pairwise)
    auto exact_check = [&](int row, int k) {
        const float* ep = enc + (n0 + row) * DIM;
        const float* wp = weight + (long)k * DIM;
        float dot = 0.0f;
        float rA[8], rB[8];
        #pragma unroll
        for (int j = 0; j < 8; ++j) { rA[j] = 0.0f; rB[j] = 0.0f; }
        #pragma unroll
        for (int dp = 0; dp < 16; ++dp) {          // first 128 dims (d4 = 2dp, 2dp+1)
            {
                const float4 ev = *(const float4*)&ep[dp * 8];
                const float4 wv = *(const float4*)&wp[dp * 8];
                dot = __fmaf_rn(ev.x, wv.x, dot); dot = __fmaf_rn(ev.y, wv.y, dot);
                dot = __fmaf_rn(ev.z, wv.z, dot); dot = __fmaf_rn(ev.w, wv.w, dot);
                rA[0] = __fadd_rn(rA[0], __fmul_rn(ev.x, ev.x));
                rA[1] = __fadd_rn(rA[1], __fmul_rn(ev.y, ev.y));
                rA[2] = __fadd_rn(rA[2], __fmul_rn(ev.z, ev.z));
                rA[3] = __fadd_rn(rA[3], __fmul_rn(ev.w, ev.w));
            }
            {
                const float4 ev = *(const float4*)&ep[dp * 8 + 4];
                const float4 wv = *(const float4*)&wp[dp * 8 + 4];
                dot = __fmaf_rn(ev.x, wv.x, dot); dot = __fmaf_rn(ev.y, wv.y, dot);
                dot = __fmaf_rn(ev.z, wv.z, dot); dot = __fmaf_rn(ev.w, wv.w, dot);
                rA[4] = __fadd_rn(rA[4], __fmul_rn(ev.x, ev.x));
                rA[5] = __fadd_rn(rA[5], __fmul_rn(ev.y, ev.y));
                rA[6] = __fadd_rn(rA[6], __fmul_rn(ev.z, ev.z));
                rA[7] = __fadd_rn(rA[7], __fmul_rn(ev.w, ev.w));
            }
        }
        #pragma unroll
        for (int dp = 0; dp < 16; ++dp) {          // second 128 dims
            {
                const float4 ev = *(const float4*)&ep[128 + dp * 8];
                const float4 wv = *(const float4*)&wp[128 + dp * 8];
                dot = __fmaf_rn(ev.x, wv.x, dot); dot = __fmaf_rn(ev.y, wv.y, dot);
                dot = __fmaf_rn(ev.z, wv.z, dot); dot = __fmaf_rn(ev.w, wv.w, dot);
                rB[0] = __fadd_rn(rB[0], __fmul_rn(ev.x, ev.x));
                rB[1] = __fadd_rn(rB[1], __fmul_rn(ev.y, ev.y));
                rB[2] = __fadd_rn(rB[2], __fmul_rn(ev.z, ev.z));
                rB[3] = __fadd_rn(rB[3], __fmul_rn(ev.w, ev.w));
            }
            {
                const float4 ev = *(const float4*)&ep[128 + dp * 8 + 4];
                const float4 wv = *(const float4*)&wp[128 + dp * 8 + 4];
                dot = __fmaf_rn(ev.x, wv.x, dot); dot = __fmaf_rn(ev.y, wv.y, dot);
                dot = __fmaf_rn(ev.z, wv.z, dot); dot = __fmaf_rn(ev.w, wv.w, dot);
                rB[4] = __fadd_rn(rB[4], __fmul_rn(ev.x, ev.x));
                rB[5] = __fadd_rn(rB[5], __fmul_rn(ev.y, ev.y));
                rB[6] = __fadd_rn(rB[6], __fmul_rn(ev.z, ev.z));
                rB[7] = __fadd_rn(rB[7], __fmul_rn(ev.w, ev.w));
            }
        }
        const float bA = __fadd_rn(__fadd_rn(__fadd_rn(rA[0], rA[1]), __fadd_rn(rA[2], rA[3])),
                                   __fadd_rn(__fadd_rn(rA[4], rA[5]), __fadd_rn(rA[6], rA[7])));
        const float bB = __fadd_rn(__fadd_rn(__fadd_rn(rB[0], rB[1]), __fadd_rn(rB[2], rB[3])),
                                   __fadd_rn(__fadd_rn(rB[4], rB[5]), __fadd_rn(rB[6], rB[7])));
        const float sEr = __fadd_rn(bA, bB);
        const float vex = __fadd_rn(__fadd_rn(sEr, -__fmul_rn(2.0f, dot)), wn[k]);
        const unsigned long long pk =
            (((unsigned long long)__float_as_uint(vex)) << 10) | (unsigned long long)k;
        atomicMin(&rmEx[row], pk);
    };

    #pragma unroll
    for (int sl = 0; sl < 8; ++sl) {               // candidate compaction
        const int row = mh * 32 + (sl >> 2) * 16 + fg * 4 + (sl & 3);
        const unsigned thr = (rm[row] >> 10) + 1000u;  // ~9.5e-4 window
        #pragma unroll
        for (int c = 0; c < 2; ++c) {
            const unsigned u = c ? s2[sl] : s1[sl];
            if ((u >> 10) <= thr) {
                const unsigned pos = atomicAdd(&lcount, 1u);
                if (pos < LCAP) list[pos] = ((unsigned)row << 10) | (u & 1023u);
                else exact_check(row, (int)(u & 1023u));
            }
        }
    }
    __syncthreads();
    {                                               // parallel exact pass
        const unsigned cnt = min(lcount, (unsigned)LCAP);
        for (unsigned t = tid; t < cnt; t += 512) {
            const unsigned ent = list[t];
            exact_check((int)(ent >> 10), (int)(ent & 1023u));
        }
    }
    __syncthreads();

    if (tid < 64) idx_out[n0 + tid] = (float)(unsigned)(rmEx[tid] & 1023ull);
}

// ================= K3: gather codes -> qf + NCHW scatter ====================
__global__ __launch_bounds__(256) void vq_gather_kernel(
    const float* __restrict__ weight, const float* __restrict__ idx_in,
    float* __restrict__ qf_out, float* __restrict__ q_out)
{
    __shared__ __align__(16) float F[32][260];
    __shared__ int kk[32];
    const int tid = threadIdx.x;
    const int blk = blockIdx.x;        // = b*32 + h
    const int b = blk >> 5, h = blk & 31;
    const long n0 = (long)blk * 32;

    if (tid < 32) kk[tid] = (int)idx_in[n0 + tid];
    __syncthreads();
    {
        const int c4 = tid & 63, rg = tid >> 6;
        #pragma unroll
        for (int r0 = 0; r0 < 32; r0 += 4) {
            const int row = r0 + rg;
            const int k = kk[row];
            const float4 v = *(const float4*)&weight[(long)k * DIM + c4 * 4];
            *(float4*)&qf_out[(n0 + row) * DIM + c4 * 4] = v;
            *(float4*)&F[row][c4 * 4] = v;
        }
    }
    __syncthreads();
    {
        const int w = tid & 31, c0 = tid >> 5;
        for (int c = c0; c < DIM; c += 8)
            q_out[(((long)b * DIM + c) * 32 + h) * 32 + w] = F[w][c];
    }
}

extern "C" void kernel_launch(void* const* d_in, const int* in_sizes, int n_in,
                              void* d_out, int out_size, void* d_ws, size_t ws_size,
                              hipStream_t stream)
{
    const float* x      = (const float*)d_in[0];   // [32,256,32,32]
    const float* weight = (const float*)d_in[1];   // [1024,256]

    float* out = (float*)d_out;
    float* enc = out;                                   // [32768,256]
    float* qf  = enc + (size_t)N_TOT * DIM;             // [32768,256]
    float* idx = qf  + (size_t)N_TOT * DIM;             // [32768] as float
    float* qo  = idx + N_TOT;                           // [32,256,32,32]

    float* wnorm = (float*)d_ws;                        // 4 KB
    f16*   Wh    = (f16*)((char*)d_ws + 4096);          // 512 KB (if it fits)

    const bool pre = ws_size >= (size_t)(4096 + K_CODES * DIM * 2 + 64);

    vq_wnorm_kernel<<<K_CODES / 256, 256, 0, stream>>>(weight, wnorm);
    vq_prep_kernel<<<1024, 256, 0, stream>>>(x, enc);
    if (pre) {
        vq_convw_kernel<<<K_CODES, 64, 0, stream>>>(weight, Wh);
        vq_dist_kernel<true><<<512, 512, 0, stream>>>(enc, weight, wnorm, Wh, idx);
    } else {
        vq_dist_kernel<false><<<512, 512, 0, stream>>>(enc, weight, wnorm, Wh, idx);
    }
    vq_gather_kernel<<<1024, 256, 0, stream>>>(weight, idx, qf, qo);
}

// Round 9
// 108.970 us; speedup vs baseline: 1.6750x; 1.2570x over previous
//
#include <hip/hip_runtime.h>

#define K_CODES 1024
#define DIM 256
#define N_TOT 32768
#define LCAP 512

typedef _Float16 f16;
typedef _Float16 f16x8 __attribute__((ext_vector_type(8)));
typedef float f32x4 __attribute__((ext_vector_type(4)));

// Exact replica of numpy FLOAT_pairwise_sum for 128 contiguous squares (validated r3).
__device__ __forceinline__ float np_pw128_sq(const float* __restrict__ v) {
    float r[8];
    #pragma unroll
    for (int j = 0; j < 8; ++j) r[j] = __fmul_rn(v[j], v[j]);
    #pragma unroll
    for (int i = 1; i < 16; ++i)
        #pragma unroll
        for (int j = 0; j < 8; ++j)
            r[j] = __fadd_rn(r[j], __fmul_rn(v[8*i+j], v[8*i+j]));
    const float t01 = __fadd_rn(r[0], r[1]);
    const float t23 = __fadd_rn(r[2], r[3]);
    const float t45 = __fadd_rn(r[4], r[5]);
    const float t67 = __fadd_rn(r[6], r[7]);
    return __fadd_rn(__fadd_rn(t01, t23), __fadd_rn(t45, t67));
}

__global__ void vq_wnorm_kernel(const float* __restrict__ weight, float* __restrict__ wnorm) {
    int k = blockIdx.x * blockDim.x + threadIdx.x;
    if (k >= K_CODES) return;
    const float* wr = weight + (size_t)k * DIM;
    wnorm[k] = __fadd_rn(np_pw128_sq(wr), np_pw128_sq(wr + 128));
}

// W -> f16 scaled by 1024 (exact pow2), stored PRE-SWIZZLED:
// within each 512B code row, 16B unit u lands at u ^ (code & 7).
// global_load_lds then copies linearly; ds_read applies the same XOR.
__global__ __launch_bounds__(64) void vq_convw_kernel(
    const float* __restrict__ weight, f16* __restrict__ Whs)
{
    const int t = threadIdx.x;
    const int code = blockIdx.x * 2 + (t >> 5);   // 512 blocks x 64 thr: 2 codes/block
    const int unit = t & 31;                      // 16B unit (8 f16 = 8 dims)
    const float4 v0 = *(const float4*)&weight[(size_t)code * DIM + unit * 8];
    const float4 v1 = *(const float4*)&weight[(size_t)code * DIM + unit * 8 + 4];
    f16x8 o;
    o[0]=(f16)(v0.x*1024.f); o[1]=(f16)(v0.y*1024.f); o[2]=(f16)(v0.z*1024.f); o[3]=(f16)(v0.w*1024.f);
    o[4]=(f16)(v1.x*1024.f); o[5]=(f16)(v1.y*1024.f); o[6]=(f16)(v1.z*1024.f); o[7]=(f16)(v1.w*1024.f);
    const int du = unit ^ (code & 7);
    *(f16x8*)&Whs[(size_t)code * DIM + du * 8] = o;
}

// ================= K1: transpose x -> encoded_flat ==========================
__global__ __launch_bounds__(256) void vq_prep_kernel(
    const float* __restrict__ x, float* __restrict__ enc_out)
{
    __shared__ __align__(16) float F[32][260];
    const int tid = threadIdx.x;
    const int blk = blockIdx.x;        // = b*32 + h
    const int b = blk >> 5, h = blk & 31;
    const long n0 = (long)blk * 32;

    {
        const int wq = tid & 7, cb = tid >> 3;
        for (int c = cb; c < DIM; c += 32) {
            const float4 v = *(const float4*)&x[(((long)b * DIM + c) * 32 + h) * 32 + wq * 4];
            F[wq * 4 + 0][c] = v.x; F[wq * 4 + 1][c] = v.y;
            F[wq * 4 + 2][c] = v.z; F[wq * 4 + 3][c] = v.w;
        }
    }
    __syncthreads();
    {
        const int c4 = tid & 63, rg = tid >> 6;
        #pragma unroll
        for (int r0 = 0; r0 < 32; r0 += 4) {
            const int row = r0 + rg;
            *(float4*)&enc_out[(n0 + row) * DIM + c4 * 4] = *(const float4*)&F[row][c4 * 4];
        }
    }
}

// ================= K2: MFMA distance + argmin, LDS-staged B =================
template<bool PRE>
__global__ __launch_bounds__(512, 2) void vq_dist_kernel(
    const float* __restrict__ enc, const float* __restrict__ weight,
    const float* __restrict__ wnorm, const f16* __restrict__ Whs,
    float* __restrict__ idx_out)
{
    __shared__ __align__(16) char Wb[2][32768];    // 64 KB double buffer (64 codes/chunk)
    __shared__ float wn[K_CODES];
    __shared__ unsigned rm[64];
    __shared__ unsigned long long rmEx[64];
    __shared__ unsigned list[LCAP];
    __shared__ unsigned lcount;

    const int tid = threadIdx.x;
    const long n0 = (long)blockIdx.x * 64;         // 512 blocks x 64 rows
    const int wid = tid >> 6, lane = tid & 63;
    const int mh = wid >> 2, qw = wid & 3;         // row-half, 16-code strip of chunk
    const int fr = lane & 15, fg = lane >> 4;

    if (tid < 64) { rm[tid] = 0xFFFFFFFFu; rmEx[tid] = 0xFFFFFFFFFFFFFFFFull; }
    if (tid == 0) lcount = 0;
    for (int i = tid; i < K_CODES; i += 512) wn[i] = wnorm[i];

    // A-fragments from enc (fp32 -> f16 in regs); 64 VGPR
    f16x8 afr[2][8];
    #pragma unroll
    for (int mt = 0; mt < 2; ++mt)
        #pragma unroll
        for (int kk = 0; kk < 8; ++kk) {
            const int row = mh * 32 + mt * 16 + fr;
            const float4 lo = *(const float4*)&enc[(n0 + row) * DIM + kk * 32 + fg * 8];
            const float4 hi = *(const float4*)&enc[(n0 + row) * DIM + kk * 32 + fg * 8 + 4];
            f16x8 a;
            a[0] = (f16)lo.x; a[1] = (f16)lo.y; a[2] = (f16)lo.z; a[3] = (f16)lo.w;
            a[4] = (f16)hi.x; a[5] = (f16)hi.y; a[6] = (f16)hi.z; a[7] = (f16)hi.w;
            afr[mt][kk] = a;
        }

    // ---- staging: chunk ch (64 codes, 32 KB) into Wb[buf] ----
    auto stage = [&](int buf, int ch) {
        if (PRE) {
            #pragma unroll
            for (int u = 0; u < 4; ++u) {
                const int off = (u * 8 + wid) * 1024;            // wave-uniform
                const char* src = (const char*)Whs + (size_t)ch * 32768 + off + lane * 16;
                __builtin_amdgcn_global_load_lds(
                    (const __attribute__((address_space(1))) void*)src,
                    (__attribute__((address_space(3))) void*)&Wb[buf][off], 16, 0, 0);
            }
        } else {
            #pragma unroll
            for (int u = 0; u < 4; ++u) {
                const int flat = u * 512 + tid;
                const int code = flat >> 5, unit = flat & 31;
                const float4 v0 = *(const float4*)&weight[(long)(ch * 64 + code) * DIM + unit * 8];
                const float4 v1 = *(const float4*)&weight[(long)(ch * 64 + code) * DIM + unit * 8 + 4];
                f16x8 t;
                t[0]=(f16)(v0.x*1024.f); t[1]=(f16)(v0.y*1024.f); t[2]=(f16)(v0.z*1024.f); t[3]=(f16)(v0.w*1024.f);
                t[4]=(f16)(v1.x*1024.f); t[5]=(f16)(v1.y*1024.f); t[6]=(f16)(v1.z*1024.f); t[7]=(f16)(v1.w*1024.f);
                *(f16x8*)&Wb[buf][code * 512 + (unit ^ (code & 7)) * 16] = t;
            }
        }
    };

    unsigned s1[8], s2[8];                         // per-slot top-2 packed (v_q<<10 | k)
    #pragma unroll
    for (int i = 0; i < 8; ++i) { s1[i] = 0xFFFFFFFFu; s2[i] = 0xFFFFFFFFu; }

    stage(0, 0);
    __syncthreads();                               // buf0 ready; inits visible

    for (int ch = 0; ch < 16; ++ch) {
        const int buf = ch & 1;
        if (ch < 15) stage(buf ^ 1, ch + 1);       // loads fly under this chunk's compute

        const int cl = qw * 16 + fr;               // code_local in chunk
        const int code = ch * 64 + cl;
        f32x4 acc0 = {0.f, 0.f, 0.f, 0.f}, acc1 = {0.f, 0.f, 0.f, 0.f};
        #pragma unroll
        for (int kk = 0; kk < 8; ++kk) {
            const f16x8 bfr = *(const f16x8*)&Wb[buf][cl * 512 + ((kk * 4 + fg) ^ (fr & 7)) * 16];
            acc0 = __builtin_amdgcn_mfma_f32_16x16x32_f16(afr[0][kk], bfr, acc0, 0, 0, 0);
            acc1 = __builtin_amdgcn_mfma_f32_16x16x32_f16(afr[1][kk], bfr, acc1, 0, 0, 0);
        }
        const float wnk = wn[code];
        #pragma unroll
        for (int q = 0; q < 4; ++q) {
            {   // M-tile 0 (slot q): vp = wn - 2*dot (dot scaled /1024)
                const float vp = fmaf(acc0[q], -0.001953125f, wnk);
                const unsigned uq = (unsigned)fmaf(vp, 1048576.0f, 1048576.0f);
                const unsigned u = uq * 1024u + (unsigned)code;
                s2[q] = min(s2[q], max(s1[q], u));
                s1[q] = min(s1[q], u);
            }
            {   // M-tile 1 (slot 4+q)
                const float vp = fmaf(acc1[q], -0.001953125f, wnk);
                const unsigned uq = (unsigned)fmaf(vp, 1048576.0f, 1048576.0f);
                const unsigned u = uq * 1024u + (unsigned)code;
                s2[4 + q] = min(s2[4 + q], max(s1[4 + q], u));
                s1[4 + q] = min(s1[4 + q], u);
            }
        }
        __syncthreads();                           // next buf staged; this buf consumed
    }

    // wave-local min over fr lanes, then merge waves via LDS atomicMin
    #pragma unroll
    for (int sl = 0; sl < 8; ++sl) {
        unsigned bmin = s1[sl];
        bmin = min(bmin, (unsigned)__shfl_xor((int)bmin, 1));
        bmin = min(bmin, (unsigned)__shfl_xor((int)bmin, 2));
        bmin = min(bmin, (unsigned)__shfl_xor((int)bmin, 4));
        bmin = min(bmin, (unsigned)__shfl_xor((int)bmin, 8));
        if (fr == 0) {
            const int row = mh * 32 + (sl >> 2) * 16 + fg * 4 + (sl & 3);
            atomicMin(&rm[row], bmin);
        }
    }
    __syncthreads();

    // exact fp32 re-check (numpy-bit-exact r3 recipe; sE computed inline pairwise)
    auto exact_check = [&](int row, int k) {
        const float* ep = enc + (n0 + row) * DIM;
        const float* wp = weight + (long)k * DIM;
        float dot = 0.0f;
        float rA[8], rB[8];
        #pragma unroll
        for (int j = 0; j < 8; ++j) { rA[j] = 0.0f; rB[j] = 0.0f; }
        #pragma unroll
        for (int dp = 0; dp < 16; ++dp) {
            {
                const float4 ev = *(const float4*)&ep[dp * 8];
                const float4 wv = *(const float4*)&wp[dp * 8];
                dot = __fmaf_rn(ev.x, wv.x, dot); dot = __fmaf_rn(ev.y, wv.y, dot);
                dot = __fmaf_rn(ev.z, wv.z, dot); dot = __fmaf_rn(ev.w, wv.w, dot);
                rA[0] = __fadd_rn(rA[0], __fmul_rn(ev.x, ev.x));
                rA[1] = __fadd_rn(rA[1], __fmul_rn(ev.y, ev.y));
                rA[2] = __fadd_rn(rA[2], __fmul_rn(ev.z, ev.z));
                rA[3] = __fadd_rn(rA[3], __fmul_rn(ev.w, ev.w));
            }
            {
                const float4 ev = *(const float4*)&ep[dp * 8 + 4];
                const float4 wv = *(const float4*)&wp[dp * 8 + 4];
                dot = __fmaf_rn(ev.x, wv.x, dot); dot = __fmaf_rn(ev.y, wv.y, dot);
                dot = __fmaf_rn(ev.z, wv.z, dot); dot = __fmaf_rn(ev.w, wv.w, dot);
                rA[4] = __fadd_rn(rA[4], __fmul_rn(ev.x, ev.x));
                rA[5] = __fadd_rn(rA[5], __fmul_rn(ev.y, ev.y));
                rA[6] = __fadd_rn(rA[6], __fmul_rn(ev.z, ev.z));
                rA[7] = __fadd_rn(rA[7], __fmul_rn(ev.w, ev.w));
            }
        }
        #pragma unroll
        for (int dp = 0; dp < 16; ++dp) {
            {
                const float4 ev = *(const float4*)&ep[128 + dp * 8];
                const float4 wv = *(const float4*)&wp[128 + dp * 8];
                dot = __fmaf_rn(ev.x, wv.x, dot); dot = __fmaf_rn(ev.y, wv.y, dot);
                dot = __fmaf_rn(ev.z, wv.z, dot); dot = __fmaf_rn(ev.w, wv.w, dot);
                rB[0] = __fadd_rn(rB[0], __fmul_rn(ev.x, ev.x));
                rB[1] = __fadd_rn(rB[1], __fmul_rn(ev.y, ev.y));
                rB[2] = __fadd_rn(rB[2], __fmul_rn(ev.z, ev.z));
                rB[3] = __fadd_rn(rB[3], __fmul_rn(ev.w, ev.w));
            }
            {
                const float4 ev = *(const float4*)&ep[128 + dp * 8 + 4];
                const float4 wv = *(const float4*)&wp[128 + dp * 8 + 4];
                dot = __fmaf_rn(ev.x, wv.x, dot); dot = __fmaf_rn(ev.y, wv.y, dot);
                dot = __fmaf_rn(ev.z, wv.z, dot); dot = __fmaf_rn(ev.w, wv.w, dot);
                rB[4] = __fadd_rn(rB[4], __fmul_rn(ev.x, ev.x));
                rB[5] = __fadd_rn(rB[5], __fmul_rn(ev.y, ev.y));
                rB[6] = __fadd_rn(rB[6], __fmul_rn(ev.z, ev.z));
                rB[7] = __fadd_rn(rB[7], __fmul_rn(ev.w, ev.w));
            }
        }
        const float bA = __fadd_rn(__fadd_rn(__fadd_rn(rA[0], rA[1]), __fadd_rn(rA[2], rA[3])),
                                   __fadd_rn(__fadd_rn(rA[4], rA[5]), __fadd_rn(rA[6], rA[7])));
        const float bB = __fadd_rn(__fadd_rn(__fadd_rn(rB[0], rB[1]), __fadd_rn(rB[2], rB[3])),
                                   __fadd_rn(__fadd_rn(rB[4], rB[5]), __fadd_rn(rB[6], rB[7])));
        const float sEr = __fadd_rn(bA, bB);
        const float vex = __fadd_rn(__fadd_rn(sEr, -__fmul_rn(2.0f, dot)), wn[k]);
        const unsigned long long pk =
            (((unsigned long long)__float_as_uint(vex)) << 10) | (unsigned long long)k;
        atomicMin(&rmEx[row], pk);
    };

    #pragma unroll
    for (int sl = 0; sl < 8; ++sl) {               // candidate compaction
        const int row = mh * 32 + (sl >> 2) * 16 + fg * 4 + (sl & 3);
        const unsigned thr = (rm[row] >> 10) + 1000u;  // ~9.5e-4 window
        #pragma unroll
        for (int c = 0; c < 2; ++c) {
            const unsigned u = c ? s2[sl] : s1[sl];
            if ((u >> 10) <= thr) {
                const unsigned pos = atomicAdd(&lcount, 1u);
                if (pos < LCAP) list[pos] = ((unsigned)row << 10) | (u & 1023u);
                else exact_check(row, (int)(u & 1023u));
            }
        }
    }
    __syncthreads();
    {                                               // parallel exact pass
        const unsigned cnt = min(lcount, (unsigned)LCAP);
        for (unsigned t = tid; t < cnt; t += 512) {
            const unsigned ent = list[t];
            exact_check((int)(ent >> 10), (int)(ent & 1023u));
        }
    }
    __syncthreads();

    if (tid < 64) idx_out[n0 + tid] = (float)(unsigned)(rmEx[tid] & 1023ull);
}

// ================= K3: gather codes -> qf + NCHW scatter ====================
__global__ __launch_bounds__(256) void vq_gather_kernel(
    const float* __restrict__ weight, const float* __restrict__ idx_in,
    float* __restrict__ qf_out, float* __restrict__ q_out)
{
    __shared__ __align__(16) float F[32][260];
    __shared__ int kk[32];
    const int tid = threadIdx.x;
    const int blk = blockIdx.x;        // = b*32 + h
    const int b = blk >> 5, h = blk & 31;
    const long n0 = (long)blk * 32;

    if (tid < 32) kk[tid] = (int)idx_in[n0 + tid];
    __syncthreads();
    {
        const int c4 = tid & 63, rg = tid >> 6;
        #pragma unroll
        for (int r0 = 0; r0 < 32; r0 += 4) {
            const int row = r0 + rg;
            const int k = kk[row];
            const float4 v = *(const float4*)&weight[(long)k * DIM + c4 * 4];
            *(float4*)&qf_out[(n0 + row) * DIM + c4 * 4] = v;
            *(float4*)&F[row][c4 * 4] = v;
        }
    }
    __syncthreads();
    {
        const int w = tid & 31, c0 = tid >> 5;
        for (int c = c0; c < DIM; c += 8)
            q_out[(((long)b * DIM + c) * 32 + h) * 32 + w] = F[w][c];
    }
}

extern "C" void kernel_launch(void* const* d_in, const int* in_sizes, int n_in,
                              void* d_out, int out_size, void* d_ws, size_t ws_size,
                              hipStream_t stream)
{
    const float* x      = (const float*)d_in[0];   // [32,256,32,32]
    const float* weight = (const float*)d_in[1];   // [1024,256]

    float* out = (float*)d_out;
    float* enc = out;                                   // [32768,256]
    float* qf  = enc + (size_t)N_TOT * DIM;             // [32768,256]
    float* idx = qf  + (size_t)N_TOT * DIM;             // [32768] as float
    float* qo  = idx + N_TOT;                           // [32,256,32,32]

    float* wnorm = (float*)d_ws;                        // 4 KB
    f16*   Whs   = (f16*)((char*)d_ws + 4096);          // 512 KB pre-swizzled f16 codebook

    const bool pre = ws_size >= (size_t)(4096 + K_CODES * DIM * 2 + 64);

    vq_wnorm_kernel<<<K_CODES / 256, 256, 0, stream>>>(weight, wnorm);
    vq_prep_kernel<<<1024, 256, 0, stream>>>(x, enc);
    if (pre) {
        vq_convw_kernel<<<K_CODES / 2, 64, 0, stream>>>(weight, Whs);
        vq_dist_kernel<true><<<512, 512, 0, stream>>>(enc, weight, wnorm, Whs, idx);
    } else {
        vq_dist_kernel<false><<<512, 512, 0, stream>>>(enc, weight, wnorm, Whs, idx);
    }
    vq_gather_kernel<<<1024, 256, 0, stream>>>(weight, idx, qf, qo);
}

// Round 10
// 89.766 us; speedup vs baseline: 2.0333x; 1.2139x over previous
//
#include <hip/hip_runtime.h>

#define K_CODES 1024
#define DIM 256
#define N_TOT 32768
#define LCAP 512

typedef _Float16 f16;
typedef _Float16 f16x8 __attribute__((ext_vector_type(8)));
typedef float f32x4 __attribute__((ext_vector_type(4)));

// Exact replica of numpy FLOAT_pairwise_sum for 128 contiguous squares (validated r3).
__device__ __forceinline__ float np_pw128_sq(const float* __restrict__ v) {
    float r[8];
    #pragma unroll
    for (int j = 0; j < 8; ++j) r[j] = __fmul_rn(v[j], v[j]);
    #pragma unroll
    for (int i = 1; i < 16; ++i)
        #pragma unroll
        for (int j = 0; j < 8; ++j)
            r[j] = __fadd_rn(r[j], __fmul_rn(v[8*i+j], v[8*i+j]));
    const float t01 = __fadd_rn(r[0], r[1]);
    const float t23 = __fadd_rn(r[2], r[3]);
    const float t45 = __fadd_rn(r[4], r[5]);
    const float t67 = __fadd_rn(r[6], r[7]);
    return __fadd_rn(__fadd_rn(t01, t23), __fadd_rn(t45, t67));
}

__global__ void vq_wnorm_kernel(const float* __restrict__ weight, float* __restrict__ wnorm) {
    int k = blockIdx.x * blockDim.x + threadIdx.x;
    if (k >= K_CODES) return;
    const float* wr = weight + (size_t)k * DIM;
    wnorm[k] = __fadd_rn(np_pw128_sq(wr), np_pw128_sq(wr + 128));
}

// W -> f16 scaled by 1024 (exact pow2), stored PRE-SWIZZLED:
// within each 512B code row, 16B unit u lands at u ^ (code & 7).
__global__ __launch_bounds__(64) void vq_convw_kernel(
    const float* __restrict__ weight, f16* __restrict__ Whs)
{
    const int t = threadIdx.x;
    const int code = blockIdx.x * 2 + (t >> 5);
    const int unit = t & 31;
    const float4 v0 = *(const float4*)&weight[(size_t)code * DIM + unit * 8];
    const float4 v1 = *(const float4*)&weight[(size_t)code * DIM + unit * 8 + 4];
    f16x8 o;
    o[0]=(f16)(v0.x*1024.f); o[1]=(f16)(v0.y*1024.f); o[2]=(f16)(v0.z*1024.f); o[3]=(f16)(v0.w*1024.f);
    o[4]=(f16)(v1.x*1024.f); o[5]=(f16)(v1.y*1024.f); o[6]=(f16)(v1.z*1024.f); o[7]=(f16)(v1.w*1024.f);
    const int du = unit ^ (code & 7);
    *(f16x8*)&Whs[(size_t)code * DIM + du * 8] = o;
}

// ======== K2 fused: transpose + enc write + MFMA distance + argmin ==========
template<bool PRE>
__global__ __launch_bounds__(512, 2) void vq_fused_kernel(
    const float* __restrict__ x, const float* __restrict__ weight,
    const float* __restrict__ wnorm, const f16* __restrict__ Whs,
    float* __restrict__ enc_out, float* __restrict__ idx_out)
{
    // Wb0 @0 (32KB), Wb1 @32768 (32KB); F (fp32 [32][260] = 33280B) overlays @32768.
    __shared__ __align__(16) char WlRaw[66048];
    __shared__ float wn[K_CODES];
    __shared__ unsigned rm[64];
    __shared__ unsigned long long rmEx[64];
    __shared__ unsigned list[LCAP];
    __shared__ unsigned lcount;

    char* const Wb0 = WlRaw;
    char* const Wb1 = WlRaw + 32768;
    float (*F)[260] = (float(*)[260])(WlRaw + 32768);

    const int tid = threadIdx.x;
    const int blk = blockIdx.x;        // 512 blocks: b = blk>>4, hp = blk&15
    const int b = blk >> 4, hp = blk & 15;
    const long n0 = (long)blk * 64;
    const int wid = tid >> 6, lane = tid & 63;
    const int mh = wid >> 2, qw = wid & 3;
    const int fr = lane & 15, fg = lane >> 4;

    // Issue stage(0) FIRST: DMA flies under the whole transpose phase.
    if (PRE) {
        const char* src = (const char*)Whs + wid * 1024 + lane * 16;
        #pragma unroll
        for (int u = 0; u < 4; ++u) {
            __builtin_amdgcn_global_load_lds(
                (const __attribute__((address_space(1))) void*)(src + u * 8192),
                (__attribute__((address_space(3))) void*)(Wb0 + (u * 8 + wid) * 1024), 16, 0, 0);
        }
    }

    if (tid < 64) { rm[tid] = 0xFFFFFFFFu; rmEx[tid] = 0xFFFFFFFFFFFFFFFFull; }
    if (tid == 0) lcount = 0;
    for (int i = tid; i < K_CODES; i += 512) wn[i] = wnorm[i];

    // ---- Phase A: transpose x -> F -> (enc_out, afr) in 2 halves of 32 rows ----
    f16x8 afr[2][8];
    for (int s = 0; s < 2; ++s) {
        const int h = hp * 2 + s;
        if (s) __syncthreads();                        // F free (skip at s=0: no drain of stage(0))
        {
            const int w = tid & 31, c0 = tid >> 5;
            for (int c = c0; c < DIM; c += 16)
                F[w][c] = x[(((long)b * DIM + c) * 32 + h) * 32 + w];
        }
        __syncthreads();
        {   // encoded_flat write (float4 coalesced)
            const int c4 = tid & 63, rg = tid >> 6;
            #pragma unroll
            for (int r0 = 0; r0 < 32; r0 += 8) {
                const int row = r0 + rg;
                *(float4*)&enc_out[(n0 + s * 32 + row) * DIM + c4 * 4] =
                    *(const float4*)&F[row][c4 * 4];
            }
        }
        if (mh == s) {   // extract this wave's A-fragments (f32 -> f16 in regs)
            #pragma unroll
            for (int mt = 0; mt < 2; ++mt)
                #pragma unroll
                for (int kk = 0; kk < 8; ++kk) {
                    const float4 lo = *(const float4*)&F[mt * 16 + fr][kk * 32 + fg * 8];
                    const float4 hi = *(const float4*)&F[mt * 16 + fr][kk * 32 + fg * 8 + 4];
                    f16x8 a;
                    a[0] = (f16)lo.x; a[1] = (f16)lo.y; a[2] = (f16)lo.z; a[3] = (f16)lo.w;
                    a[4] = (f16)hi.x; a[5] = (f16)hi.y; a[6] = (f16)hi.z; a[7] = (f16)hi.w;
                    afr[mt][kk] = a;
                }
        }
    }

    // ---- staging helper: chunk ch (64 codes, 32 KB) into dst buffer ----
    auto stage = [&](char* dst, int ch) {
        if (PRE) {
            const char* src = (const char*)Whs + (size_t)ch * 32768 + wid * 1024 + lane * 16;
            #pragma unroll
            for (int u = 0; u < 4; ++u) {
                __builtin_amdgcn_global_load_lds(
                    (const __attribute__((address_space(1))) void*)(src + u * 8192),
                    (__attribute__((address_space(3))) void*)(dst + (u * 8 + wid) * 1024), 16, 0, 0);
            }
        } else {
            #pragma unroll
            for (int u = 0; u < 4; ++u) {
                const int flat = u * 512 + tid;
                const int code = flat >> 5, unit = flat & 31;
                const float4 v0 = *(const float4*)&weight[(long)(ch * 64 + code) * DIM + unit * 8];
                const float4 v1 = *(const float4*)&weight[(long)(ch * 64 + code) * DIM + unit * 8 + 4];
                f16x8 t;
                t[0]=(f16)(v0.x*1024.f); t[1]=(f16)(v0.y*1024.f); t[2]=(f16)(v0.z*1024.f); t[3]=(f16)(v0.w*1024.f);
                t[4]=(f16)(v1.x*1024.f); t[5]=(f16)(v1.y*1024.f); t[6]=(f16)(v1.z*1024.f); t[7]=(f16)(v1.w*1024.f);
                *(f16x8*)(dst + code * 512 + (unit ^ (code & 7)) * 16) = t;
            }
        }
    };

    __syncthreads();                                   // F dead; stage(0) drained
    if (!PRE) { stage(Wb0, 0); __syncthreads(); }

    // ---- Phase B: chunk loop (r9-validated) ----
    unsigned s1[8], s2[8];
    #pragma unroll
    for (int i = 0; i < 8; ++i) { s1[i] = 0xFFFFFFFFu; s2[i] = 0xFFFFFFFFu; }

    for (int ch = 0; ch < 16; ++ch) {
        char* const bufp = (ch & 1) ? Wb1 : Wb0;
        if (ch < 15) stage((ch & 1) ? Wb0 : Wb1, ch + 1);   // flies under compute

        const int cl = qw * 16 + fr;
        const int code = ch * 64 + cl;
        f32x4 acc0 = {0.f, 0.f, 0.f, 0.f}, acc1 = {0.f, 0.f, 0.f, 0.f};
        #pragma unroll
        for (int kk = 0; kk < 8; ++kk) {
            const f16x8 bfr = *(const f16x8*)(bufp + cl * 512 + (((kk * 4 + fg) ^ (fr & 7)) * 16));
            acc0 = __builtin_amdgcn_mfma_f32_16x16x32_f16(afr[0][kk], bfr, acc0, 0, 0, 0);
            acc1 = __builtin_amdgcn_mfma_f32_16x16x32_f16(afr[1][kk], bfr, acc1, 0, 0, 0);
        }
        const float wnk = wn[code];
        #pragma unroll
        for (int q = 0; q < 4; ++q) {
            {   // M-tile 0 (slot q): vp = wn - 2*dot (dot scaled /1024)
                const float vp = fmaf(acc0[q], -0.001953125f, wnk);
                const unsigned uq = (unsigned)fmaf(vp, 1048576.0f, 1048576.0f);
                const unsigned u = uq * 1024u + (unsigned)code;
                s2[q] = min(s2[q], max(s1[q], u));
                s1[q] = min(s1[q], u);
            }
            {   // M-tile 1 (slot 4+q)
                const float vp = fmaf(acc1[q], -0.001953125f, wnk);
                const unsigned uq = (unsigned)fmaf(vp, 1048576.0f, 1048576.0f);
                const unsigned u = uq * 1024u + (unsigned)code;
                s2[4 + q] = min(s2[4 + q], max(s1[4 + q], u));
                s1[4 + q] = min(s1[4 + q], u);
            }
        }
        __syncthreads();                               // next buf staged; this buf consumed
    }

    // ---- approximate per-row min ----
    #pragma unroll
    for (int sl = 0; sl < 8; ++sl) {
        unsigned bmin = s1[sl];
        bmin = min(bmin, (unsigned)__shfl_xor((int)bmin, 1));
        bmin = min(bmin, (unsigned)__shfl_xor((int)bmin, 2));
        bmin = min(bmin, (unsigned)__shfl_xor((int)bmin, 4));
        bmin = min(bmin, (unsigned)__shfl_xor((int)bmin, 8));
        if (fr == 0) {
            const int row = mh * 32 + (sl >> 2) * 16 + fg * 4 + (sl & 3);
            atomicMin(&rm[row], bmin);
        }
    }
    __syncthreads();

    // ---- exact fp32 re-check (numpy-bit-exact r3 recipe; sE inline pairwise) ----
    auto exact_check = [&](int row, int k) {
        const float* ep = enc_out + (n0 + row) * DIM;
        const float* wp = weight + (long)k * DIM;
        float dot = 0.0f;
        float rA[8], rB[8];
        #pragma unroll
        for (int j = 0; j < 8; ++j) { rA[j] = 0.0f; rB[j] = 0.0f; }
        #pragma unroll
        for (int dp = 0; dp < 16; ++dp) {
            {
                const float4 ev = *(const float4*)&ep[dp * 8];
                const float4 wv = *(const float4*)&wp[dp * 8];
                dot = __fmaf_rn(ev.x, wv.x, dot); dot = __fmaf_rn(ev.y, wv.y, dot);
                dot = __fmaf_rn(ev.z, wv.z, dot); dot = __fmaf_rn(ev.w, wv.w, dot);
                rA[0] = __fadd_rn(rA[0], __fmul_rn(ev.x, ev.x));
                rA[1] = __fadd_rn(rA[1], __fmul_rn(ev.y, ev.y));
                rA[2] = __fadd_rn(rA[2], __fmul_rn(ev.z, ev.z));
                rA[3] = __fadd_rn(rA[3], __fmul_rn(ev.w, ev.w));
            }
            {
                const float4 ev = *(const float4*)&ep[dp * 8 + 4];
                const float4 wv = *(const float4*)&wp[dp * 8 + 4];
                dot = __fmaf_rn(ev.x, wv.x, dot); dot = __fmaf_rn(ev.y, wv.y, dot);
                dot = __fmaf_rn(ev.z, wv.z, dot); dot = __fmaf_rn(ev.w, wv.w, dot);
                rA[4] = __fadd_rn(rA[4], __fmul_rn(ev.x, ev.x));
                rA[5] = __fadd_rn(rA[5], __fmul_rn(ev.y, ev.y));
                rA[6] = __fadd_rn(rA[6], __fmul_rn(ev.z, ev.z));
                rA[7] = __fadd_rn(rA[7], __fmul_rn(ev.w, ev.w));
            }
        }
        #pragma unroll
        for (int dp = 0; dp < 16; ++dp) {
            {
                const float4 ev = *(const float4*)&ep[128 + dp * 8];
                const float4 wv = *(const float4*)&wp[128 + dp * 8];
                dot = __fmaf_rn(ev.x, wv.x, dot); dot = __fmaf_rn(ev.y, wv.y, dot);
                dot = __fmaf_rn(ev.z, wv.z, dot); dot = __fmaf_rn(ev.w, wv.w, dot);
                rB[0] = __fadd_rn(rB[0], __fmul_rn(ev.x, ev.x));
                rB[1] = __fadd_rn(rB[1], __fmul_rn(ev.y, ev.y));
                rB[2] = __fadd_rn(rB[2], __fmul_rn(ev.z, ev.z));
                rB[3] = __fadd_rn(rB[3], __fmul_rn(ev.w, ev.w));
            }
            {
                const float4 ev = *(const float4*)&ep[128 + dp * 8 + 4];
                const float4 wv = *(const float4*)&wp[128 + dp * 8 + 4];
                dot = __fmaf_rn(ev.x, wv.x, dot); dot = __fmaf_rn(ev.y, wv.y, dot);
                dot = __fmaf_rn(ev.z, wv.z, dot); dot = __fmaf_rn(ev.w, wv.w, dot);
                rB[4] = __fadd_rn(rB[4], __fmul_rn(ev.x, ev.x));
                rB[5] = __fadd_rn(rB[5], __fmul_rn(ev.y, ev.y));
                rB[6] = __fadd_rn(rB[6], __fmul_rn(ev.z, ev.z));
                rB[7] = __fadd_rn(rB[7], __fmul_rn(ev.w, ev.w));
            }
        }
        const float bA = __fadd_rn(__fadd_rn(__fadd_rn(rA[0], rA[1]), __fadd_rn(rA[2], rA[3])),
                                   __fadd_rn(__fadd_rn(rA[4], rA[5]), __fadd_rn(rA[6], rA[7])));
        const float bB = __fadd_rn(__fadd_rn(__fadd_rn(rB[0], rB[1]), __fadd_rn(rB[2], rB[3])),
                                   __fadd_rn(__fadd_rn(rB[4], rB[5]), __fadd_rn(rB[6], rB[7])));
        const float sEr = __fadd_rn(bA, bB);
        const float vex = __fadd_rn(__fadd_rn(sEr, -__fmul_rn(2.0f, dot)), wn[k]);
        const unsigned long long pk =
            (((unsigned long long)__float_as_uint(vex)) << 10) | (unsigned long long)k;
        atomicMin(&rmEx[row], pk);
    };

    #pragma unroll
    for (int sl = 0; sl < 8; ++sl) {                   // candidate compaction
        const int row = mh * 32 + (sl >> 2) * 16 + fg * 4 + (sl & 3);
        const unsigned thr = (rm[row] >> 10) + 1000u;  // ~9.5e-4 window
        #pragma unroll
        for (int c = 0; c < 2; ++c) {
            const unsigned u = c ? s2[sl] : s1[sl];
            if ((u >> 10) <= thr) {
                const unsigned pos = atomicAdd(&lcount, 1u);
                if (pos < LCAP) list[pos] = ((unsigned)row << 10) | (u & 1023u);
                else exact_check(row, (int)(u & 1023u));
            }
        }
    }
    __syncthreads();
    {                                                   // parallel exact pass
        const unsigned cnt = min(lcount, (unsigned)LCAP);
        for (unsigned t = tid; t < cnt; t += 512) {
            const unsigned ent = list[t];
            exact_check((int)(ent >> 10), (int)(ent & 1023u));
        }
    }
    __syncthreads();

    if (tid < 64) idx_out[n0 + tid] = (float)(unsigned)(rmEx[tid] & 1023ull);
}

// ================= K3: gather codes -> qf + NCHW scatter ====================
__global__ __launch_bounds__(256) void vq_gather_kernel(
    const float* __restrict__ weight, const float* __restrict__ idx_in,
    float* __restrict__ qf_out, float* __restrict__ q_out)
{
    __shared__ __align__(16) float F[32][260];
    __shared__ int kk[32];
    const int tid = threadIdx.x;
    const int blk = blockIdx.x;        // = b*32 + h
    const int b = blk >> 5, h = blk & 31;
    const long n0 = (long)blk * 32;

    if (tid < 32) kk[tid] = (int)idx_in[n0 + tid];
    __syncthreads();
    {
        const int c4 = tid & 63, rg = tid >> 6;
        #pragma unroll
        for (int r0 = 0; r0 < 32; r0 += 4) {
            const int row = r0 + rg;
            const int k = kk[row];
            const float4 v = *(const float4*)&weight[(long)k * DIM + c4 * 4];
            *(float4*)&qf_out[(n0 + row) * DIM + c4 * 4] = v;
            *(float4*)&F[row][c4 * 4] = v;
        }
    }
    __syncthreads();
    {
        const int w = tid & 31, c0 = tid >> 5;
        for (int c = c0; c < DIM; c += 8)
            q_out[(((long)b * DIM + c) * 32 + h) * 32 + w] = F[w][c];
    }
}

extern "C" void kernel_launch(void* const* d_in, const int* in_sizes, int n_in,
                              void* d_out, int out_size, void* d_ws, size_t ws_size,
                              hipStream_t stream)
{
    const float* x      = (const float*)d_in[0];   // [32,256,32,32]
    const float* weight = (const float*)d_in[1];   // [1024,256]

    float* out = (float*)d_out;
    float* enc = out;                                   // [32768,256]
    float* qf  = enc + (size_t)N_TOT * DIM;             // [32768,256]
    float* idx = qf  + (size_t)N_TOT * DIM;             // [32768] as float
    float* qo  = idx + N_TOT;                           // [32,256,32,32]

    float* wnorm = (float*)d_ws;                        // 4 KB
    f16*   Whs   = (f16*)((char*)d_ws + 4096);          // 512 KB pre-swizzled f16 codebook

    const bool pre = ws_size >= (size_t)(4096 + K_CODES * DIM * 2 + 64);

    vq_wnorm_kernel<<<K_CODES / 256, 256, 0, stream>>>(weight, wnorm);
    if (pre) {
        vq_convw_kernel<<<K_CODES / 2, 64, 0, stream>>>(weight, Whs);
        vq_fused_kernel<true><<<512, 512, 0, stream>>>(x, weight, wnorm, Whs, enc, idx);
    } else {
        vq_fused_kernel<false><<<512, 512, 0, stream>>>(x, weight, wnorm, Whs, enc, idx);
    }
    vq_gather_kernel<<<1024, 256, 0, stream>>>(weight, idx, qf, qo);
}